// Round 1
// baseline (4250.282 us; speedup 1.0000x reference)
//
#include <hip/hip_runtime.h>
#include <hip/hip_bf16.h>

// LSTM: B=64, T=512, IN=512, H=1024, gates i,f,g,o.
// Persistent kernel, 128 blocks x 256 threads.
// R9: LATENCY-CHAIN OVERLAP. The per-step serial path was:
//   poll -> DMA(32KB h + 16KB x) -> vmcnt(0) -> F(64 MFMA) -> epi -> store
//   -> drain -> signal,  with the A-loop hidden only in the poll shadow.
// Changes (all on the serial path, sync protocol untouched):
//  1) h-DMA issued as two half-row batches (16+16 instrs); F-loop split
//     kt0-15 / kt16-31 behind counted vmcnt(32)/vmcnt(16) -> half the h
//     transfer hides under F compute (in-order vmcnt retirement).
//  2) A-loop moved between DMA-issue and first counted wait -> its ~400cy
//     overlap the h0 transfer for EVERY wave (incl. the straggler).
//  3) x-prefetch issued after the h batches (counted in the 48-outstanding
//     budget) -> off the F-entry wait; drains lazily, fully retired by the
//     pre-signal vmcnt(0) so the next poll waits on nothing.
//  4) acquire-fence period 32 -> 64 (reuse distance NBUF=65 > 64: every
//     65-step window still contains >=1 fence) -> half the L2 refetch storms.
// sched_barrier(0) pins the h0 | h1 | x issue-group order so the
// hand-counted vmcnt values stay exact.
// R8 retained: wave-specialized chains (4 independent per-wave-index sync
// domains, 8-leaf x 16-writer atomic trees, 8-lane poll, no __syncthreads
// in the loop), 65 rotating h buffers, sc1 h stores, cached global_load_lds
// DMA, W_hh in regs, W_ih bf16 in LDS, XOR swizzle everywhere.

#define Bx 64
#define Tx 512
#define INx 512
#define Hx 1024
#define NBLK 128
#define UNITS 8
#define NBUF 65            // rotating h buffers

typedef __attribute__((ext_vector_type(8))) short short8;
typedef __attribute__((ext_vector_type(4))) float floatx4;

// normal cached direct-to-LDS copy (L2-allocating)
#define ASYNC_CP(gp, lp)                                                      \
  __builtin_amdgcn_global_load_lds(                                           \
      (const __attribute__((address_space(1))) void*)(gp),                    \
      (__attribute__((address_space(3))) void*)(lp), 16, 0, 0)

__device__ __forceinline__ unsigned short f2bf(float f) {
  unsigned u = __float_as_uint(f);
  u += 0x7FFFu + ((u >> 16) & 1u);   // round-to-nearest-even
  return (unsigned short)(u >> 16);
}
__device__ __forceinline__ float sigm(float x) { return 1.0f / (1.0f + __expf(-x)); }
__device__ __forceinline__ float tanh_(float x) { return 1.0f - 2.0f / (1.0f + __expf(2.0f * x)); }

// Convert input [B][T][IN] fp32 -> xT [T][B][IN] bf16
__global__ void convert_x_kernel(const float* __restrict__ in, unsigned short* __restrict__ xT) {
  int idx = blockIdx.x * 256 + threadIdx.x;
  int lin = idx * 8;
  int t = lin >> 15;
  int rem = lin & 32767;
  int b = rem >> 9;
  int k = rem & 511;
  const float* src = in + ((((b << 9) + t) << 9) + k);
  float4 lo = *(const float4*)src;
  float4 hi = *(const float4*)(src + 4);
  short8 o;
  o[0] = (short)f2bf(lo.x); o[1] = (short)f2bf(lo.y);
  o[2] = (short)f2bf(lo.z); o[3] = (short)f2bf(lo.w);
  o[4] = (short)f2bf(hi.x); o[5] = (short)f2bf(hi.y);
  o[6] = (short)f2bf(hi.z); o[7] = (short)f2bf(hi.w);
  *(short8*)(xT + lin) = o;
}

__global__ __launch_bounds__(256, 1) void lstm_persistent(
    const float* __restrict__ W_ih, const float* __restrict__ W_hh,
    const float* __restrict__ b_ih, const float* __restrict__ b_hh,
    const unsigned short* __restrict__ xT,   // [T][B][IN] bf16
    unsigned short* __restrict__ hbuf,       // [NBUF][B][H] bf16 (buf 0 zeroed)
    unsigned int* __restrict__ bar,          // 4 chains x 8 leaves x 32 uints
    float* __restrict__ out)                 // [B][H] fp32
{
  // h: 64 rows x 1024 shorts, 16B-chunk c of row m at c^(m&7)   (128 KiB)
  // wih: 32 rows x 512 shorts, chunk c of row n at c^(n&7)      (32 KiB)
  __shared__ short hsh[Bx * Hx];
  __shared__ short wsh[32 * INx];

  const int tid = threadIdx.x;
  const int lane = tid & 63;
  const int wv = tid >> 6;
  const int quad = lane >> 4;
  const int col = lane & 15;
  const int swz = col & 7;
  const int bid = blockIdx.x;
  const int j0 = bid * UNITS;
  const int m0 = wv * 16;            // batch-row base for this wave (wave-owned)

  unsigned int* leaf = bar + wv * 256;   // this chain's 8 leaves (128B stride)

  // ---- stage W_ih slice (fp32 -> bf16, swizzled) into LDS ----
  for (int idx = tid; idx < 32 * INx; idx += 256) {
    int n = idx >> 9;
    int k = idx & (INx - 1);
    int row = ((n >> 3) * Hx) + j0 + (n & 7);
    int c = k >> 3;
    wsh[n * INx + (((c ^ (n & 7)) << 3) | (k & 7))] = f2bf(W_ih[row * INx + k]);
  }

  // ---- preload W_hh B-fragments into registers ----
  short8 wf[32][2];
#pragma unroll
  for (int kt = 0; kt < 32; ++kt) {
#pragma unroll
    for (int nt = 0; nt < 2; ++nt) {
      int n = nt * 16 + col;
      int row = ((n >> 3) * Hx) + j0 + (n & 7);
      const float* p = W_hh + row * Hx + kt * 32 + quad * 8;
      short8 w;
#pragma unroll
      for (int j = 0; j < 8; ++j) w[j] = (short)f2bf(p[j]);
      wf[kt][nt] = w;
    }
  }

  // ---- bias registers: thread owns (m=m0+col, units j0+2*quad+{0,1}) ----
  float bias[2][4];
#pragma unroll
  for (int p = 0; p < 2; ++p) {
    int jl = 2 * quad + p;
#pragma unroll
    for (int gt = 0; gt < 4; ++gt) {
      int row = gt * Hx + j0 + jl;
      bias[p][gt] = b_ih[row] + b_hh[row];
    }
  }

  float cst[2] = {0.0f, 0.0f};
  float hst[2] = {0.0f, 0.0f};

  // ---- prefetch x A-frags for t=0 ----
  short8 xa[16];
  {
    const unsigned short* xrow = xT + (m0 + col) * INx + quad * 8;
#pragma unroll
    for (int kt = 0; kt < 16; ++kt) xa[kt] = *(const short8*)(xrow + kt * 32);
  }

  __syncthreads();   // wsh staging complete (only pre-loop barrier)

  int ridx = 0;                      // buffer holding h(t)
  for (int t = 0; t < Tx; ++t) {
    // ---- B: wait for this chain's h(t): all 128 blocks' wave wv ----
    // (x(t) prefetch loads were fully drained by the pre-signal vmcnt(0)
    //  last iteration, so the poll load is the only outstanding vmem.)
    {
      unsigned target = (unsigned)t * 16u;
      for (;;) {
        unsigned v = target;
        if (lane < 8)
          v = __hip_atomic_load(&leaf[lane * 32], __ATOMIC_RELAXED,
                                __HIP_MEMORY_SCOPE_AGENT);
        if (__all(v >= target)) break;
        __builtin_amdgcn_s_sleep(1);
      }
    }
    asm volatile("" ::: "memory");   // no DMA hoisting above the spin

    // every 64 steps: L2 invalidate so no stale line survives to an
    // h-buffer address reuse (reuse distance NBUF=65 > fence period 64,
    // so any reuse window contains >=1 acquire)
    if ((t & 63) == 0 && t) {
      __builtin_amdgcn_fence(__ATOMIC_ACQUIRE, "agent");
    }

    // ---- D: stage this wave's 16 h rows into LDS in TWO half-row
    //      batches; issue order (h0 x16, h1 x16, x x16) defines the
    //      counted vmcnt waits below ----
    int widx = ridx + 1; if (widx == NBUF) widx = 0;
    const unsigned short* hin = hbuf + (size_t)ridx * (Bx * Hx);
    unsigned short* hout = hbuf + (size_t)widx * (Bx * Hx);
    ridx = widx;
#pragma unroll
    for (int r = 0; r < 16; ++r) {   // half 0: row bytes [0,1024)
      const unsigned short* g = hin + (m0 + r) * Hx + ((lane ^ (r & 7)) << 3);
      short* l = hsh + (m0 + r) * Hx;
      ASYNC_CP(g, l);
    }
    __builtin_amdgcn_sched_barrier(0);   // keep h0 group oldest
#pragma unroll
    for (int r = 0; r < 16; ++r) {   // half 1: row bytes [1024,2048)
      const unsigned short* g = hin + (m0 + r) * Hx + 512 + ((lane ^ (r & 7)) << 3);
      short* l = hsh + (m0 + r) * Hx + 512;
      ASYNC_CP(g, l);
    }
    __builtin_amdgcn_sched_barrier(0);   // h1 group before anything later

    // ---- A: input part (no h dependency) OVERLAPS h0/h1 transfer ----
    floatx4 a0a = {0.f, 0.f, 0.f, 0.f}, a0b = {0.f, 0.f, 0.f, 0.f};
    floatx4 a1a = {0.f, 0.f, 0.f, 0.f}, a1b = {0.f, 0.f, 0.f, 0.f};
    {
      const short* b0base = wsh + col * INx;
      const short* b1base = wsh + (col + 16) * INx;
#pragma unroll
      for (int kt = 0; kt < 16; ++kt) {
        int off = (((kt << 2) | quad) ^ swz) << 3;
        short8 b0 = *(const short8*)(b0base + off);
        short8 b1 = *(const short8*)(b1base + off);
        if (kt & 1) {
          a0b = __builtin_amdgcn_mfma_f32_16x16x32_bf16(xa[kt], b0, a0b, 0, 0, 0);
          a1b = __builtin_amdgcn_mfma_f32_16x16x32_bf16(xa[kt], b1, a1b, 0, 0, 0);
        } else {
          a0a = __builtin_amdgcn_mfma_f32_16x16x32_bf16(xa[kt], b0, a0a, 0, 0, 0);
          a1a = __builtin_amdgcn_mfma_f32_16x16x32_bf16(xa[kt], b1, a1a, 0, 0, 0);
        }
      }
    }

    // ---- E: x-prefetch for t+1, issued AFTER the h batches (newest 16
    //      in the vmcnt stream -> never on the F-entry waits) ----
    __builtin_amdgcn_sched_barrier(0);   // x group strictly after h groups
    {
      int tn = (t + 1) & (Tx - 1);
      const unsigned short* xrow =
          xT + (size_t)tn * (Bx * INx) + (m0 + col) * INx + quad * 8;
#pragma unroll
      for (int kt = 0; kt < 16; ++kt) xa[kt] = *(const short8*)(xrow + kt * 32);
    }
    __builtin_amdgcn_sched_barrier(0);

    // ---- F: recurrent part, split behind counted waits ----
    // outstanding here: h0(16) + h1(16) + x(16) = 48; in-order retirement:
    // vmcnt(32) == h0 landed, vmcnt(16) == h1 landed (x may stay in flight)
    const short* ab = hsh + (m0 + col) * Hx;
    asm volatile("s_waitcnt vmcnt(32)" ::: "memory");
#pragma unroll
    for (int kt = 0; kt < 16; ++kt) {   // reads row bytes [0,1024) only
      short8 af = *(const short8*)(ab + ((((kt << 2) | quad) ^ swz) << 3));
      if (kt & 1) {
        a0b = __builtin_amdgcn_mfma_f32_16x16x32_bf16(af, wf[kt][0], a0b, 0, 0, 0);
        a1b = __builtin_amdgcn_mfma_f32_16x16x32_bf16(af, wf[kt][1], a1b, 0, 0, 0);
      } else {
        a0a = __builtin_amdgcn_mfma_f32_16x16x32_bf16(af, wf[kt][0], a0a, 0, 0, 0);
        a1a = __builtin_amdgcn_mfma_f32_16x16x32_bf16(af, wf[kt][1], a1a, 0, 0, 0);
      }
    }
    asm volatile("s_waitcnt vmcnt(16)" ::: "memory");
#pragma unroll
    for (int kt = 16; kt < 32; ++kt) {  // reads row bytes [1024,2048)
      short8 af = *(const short8*)(ab + ((((kt << 2) | quad) ^ swz) << 3));
      if (kt & 1) {
        a0b = __builtin_amdgcn_mfma_f32_16x16x32_bf16(af, wf[kt][0], a0b, 0, 0, 0);
        a1b = __builtin_amdgcn_mfma_f32_16x16x32_bf16(af, wf[kt][1], a1b, 0, 0, 0);
      } else {
        a0a = __builtin_amdgcn_mfma_f32_16x16x32_bf16(af, wf[kt][0], a0a, 0, 0, 0);
        a1a = __builtin_amdgcn_mfma_f32_16x16x32_bf16(af, wf[kt][1], a1a, 0, 0, 0);
      }
    }
    floatx4 acc0 = a0a + a0b;
    floatx4 acc1 = a1a + a1b;

    // ---- G: transpose gates via per-wave scratch on own h region ----
    float* gp = (float*)(hsh + wv * 16 * Hx);
#pragma unroll
    for (int i = 0; i < 4; ++i) {
      gp[(quad * 4 + i) * 33 + col] = acc0[i];
      gp[(quad * 4 + i) * 33 + 16 + col] = acc1[i];
    }

    // ---- H: activations; thread owns (m=m0+col, units jl=2*quad+{0,1}) ----
    unsigned int hpack = 0;
#pragma unroll
    for (int p = 0; p < 2; ++p) {
      int jl = 2 * quad + p;
      float gi = gp[col * 33 + jl] + bias[p][0];
      float gf = gp[col * 33 + 8 + jl] + bias[p][1];
      float gg = gp[col * 33 + 16 + jl] + bias[p][2];
      float go = gp[col * 33 + 24 + jl] + bias[p][3];
      float iv = sigm(gi);
      float fv = sigm(gf);
      float gv = tanh_(gg);
      float ov = sigm(go);
      float c = fv * cst[p] + iv * gv;
      cst[p] = c;
      float h = ov * tanh_(c);
      hst[p] = h;
      hpack |= ((unsigned int)f2bf(h)) << (16 * p);
    }
    // device-scope (sc1) packed store: write-through to LLC
    __hip_atomic_store(
        (unsigned int*)(hout + (m0 + col) * Hx + j0 + 2 * quad), hpack,
        __ATOMIC_RELAXED, __HIP_MEMORY_SCOPE_AGENT);

    // ---- I: per-wave drain + leaf signal (no block rendezvous) ----
    // vmcnt(0): h stores at LLC (also drains the x(t+1) tail, so next
    // iteration's poll load is the only outstanding vmem);
    // lgkmcnt(0): gp scratch reads done (closes WAR against next
    // iteration's DMA into the same LDS region).
    asm volatile("s_waitcnt vmcnt(0) lgkmcnt(0)" ::: "memory");
    if (lane == 0) {
      __hip_atomic_fetch_add(&leaf[(bid & 7) * 32], 1u, __ATOMIC_RELAXED,
                             __HIP_MEMORY_SCOPE_AGENT);
    }
  }

  // ---- final h -> out [B][1][H] ----
#pragma unroll
  for (int p = 0; p < 2; ++p) {
    int jl = 2 * quad + p;
    out[(m0 + col) * Hx + j0 + jl] = hst[p];
  }
}

extern "C" void kernel_launch(void* const* d_in, const int* in_sizes, int n_in,
                              void* d_out, int out_size, void* d_ws, size_t ws_size,
                              hipStream_t stream) {
  const float* input = (const float*)d_in[0];   // [B][T][IN]
  const float* W_ih  = (const float*)d_in[1];   // [4H][IN]
  const float* W_hh  = (const float*)d_in[2];   // [4H][H]
  const float* b_ih  = (const float*)d_in[3];   // [4H]
  const float* b_hh  = (const float*)d_in[4];   // [4H]
  float* out = (float*)d_out;

  char* ws = (char*)d_ws;
  unsigned int* bar = (unsigned int*)ws;                          // 4 KB
  unsigned short* hbuf = (unsigned short*)(ws + 8192);            // 65 x 128 KB
  unsigned short* xT = (unsigned short*)(ws + (9u << 20));        // 32 MB @ +9 MB

  // zero 4 chains' leaves + h buffer 0 (initial state)
  hipMemsetAsync(ws, 0, 8192 + Bx * Hx * sizeof(unsigned short), stream);

  convert_x_kernel<<<(Bx * Tx * INx) / (256 * 8), 256, 0, stream>>>(input, xT);

  lstm_persistent<<<NBLK, 256, 0, stream>>>(W_ih, W_hh, b_ih, b_hh, xT, hbuf, bar, out);
}

// Round 2
// 4085.349 us; speedup vs baseline: 1.0404x; 1.0404x over previous
//
#include <hip/hip_runtime.h>
#include <hip/hip_bf16.h>

// LSTM: B=64, T=512, IN=512, H=1024, gates i,f,g,o.
// Persistent kernel, 128 blocks x 256 threads.
// R10: R8 skeleton restored (R9's counted-vmcnt split regressed 50%: the
// compiler inserts its own vmcnt(0) before any ds_read that could alias an
// outstanding global_load_lds, so an A-loop placed between DMA-issue and
// drain stalls on the full transfer AND leaves the poll shadow).
// Changes vs R8, all on the sync-latency chain, none between a DMA group
// and its drain:
//  1) A-loop (input GEMM, LDS+regs only, no vmem) moved to between the
//     h-store and the pre-signal vmcnt(0): the ~450cy store-to-LLC drain
//     now hides under A for every wave incl. the straggler; A stays off
//     the post-poll-detect path. A(0) is computed once before the loop.
//  2) Signal tree widened 8 leaves x 16 writers -> 16 leaves x 8 writers
//     (same protocol, target = t*8): halves the same-line atomic-RMW
//     serialization tail of the last signer.
//  3) Acquire-fence period 32 -> 64 (NBUF=65 > 64: every h-buffer address
//     reuse window still contains >=1 fence) -> half the L2 refetch storms.
// R8 retained: wave-specialized chains (4 independent per-wave-index sync
// domains, no __syncthreads in the loop), 65 rotating h buffers, sc1 h
// stores, cached global_load_lds DMA, W_hh in regs, W_ih bf16 in LDS,
// XOR swizzle everywhere (conflict-free, zero padding).

#define Bx 64
#define Tx 512
#define INx 512
#define Hx 1024
#define NBLK 128
#define UNITS 8
#define NBUF 65            // rotating h buffers

typedef __attribute__((ext_vector_type(8))) short short8;
typedef __attribute__((ext_vector_type(4))) float floatx4;

// normal cached direct-to-LDS copy (L2-allocating)
#define ASYNC_CP(gp, lp)                                                      \
  __builtin_amdgcn_global_load_lds(                                           \
      (const __attribute__((address_space(1))) void*)(gp),                    \
      (__attribute__((address_space(3))) void*)(lp), 16, 0, 0)

__device__ __forceinline__ unsigned short f2bf(float f) {
  unsigned u = __float_as_uint(f);
  u += 0x7FFFu + ((u >> 16) & 1u);   // round-to-nearest-even
  return (unsigned short)(u >> 16);
}
__device__ __forceinline__ float sigm(float x) { return 1.0f / (1.0f + __expf(-x)); }
__device__ __forceinline__ float tanh_(float x) { return 1.0f - 2.0f / (1.0f + __expf(2.0f * x)); }

// Convert input [B][T][IN] fp32 -> xT [T][B][IN] bf16
__global__ void convert_x_kernel(const float* __restrict__ in, unsigned short* __restrict__ xT) {
  int idx = blockIdx.x * 256 + threadIdx.x;
  int lin = idx * 8;
  int t = lin >> 15;
  int rem = lin & 32767;
  int b = rem >> 9;
  int k = rem & 511;
  const float* src = in + ((((b << 9) + t) << 9) + k);
  float4 lo = *(const float4*)src;
  float4 hi = *(const float4*)(src + 4);
  short8 o;
  o[0] = (short)f2bf(lo.x); o[1] = (short)f2bf(lo.y);
  o[2] = (short)f2bf(lo.z); o[3] = (short)f2bf(lo.w);
  o[4] = (short)f2bf(hi.x); o[5] = (short)f2bf(hi.y);
  o[6] = (short)f2bf(hi.z); o[7] = (short)f2bf(hi.w);
  *(short8*)(xT + lin) = o;
}

__global__ __launch_bounds__(256, 1) void lstm_persistent(
    const float* __restrict__ W_ih, const float* __restrict__ W_hh,
    const float* __restrict__ b_ih, const float* __restrict__ b_hh,
    const unsigned short* __restrict__ xT,   // [T][B][IN] bf16
    unsigned short* __restrict__ hbuf,       // [NBUF][B][H] bf16 (buf 0 zeroed)
    unsigned int* __restrict__ bar,          // 4 chains x 16 leaves x 32 uints
    float* __restrict__ out)                 // [B][H] fp32
{
  // h: 64 rows x 1024 shorts, 16B-chunk c of row m at c^(m&7)   (128 KiB)
  // wih: 32 rows x 512 shorts, chunk c of row n at c^(n&7)      (32 KiB)
  __shared__ short hsh[Bx * Hx];
  __shared__ short wsh[32 * INx];

  const int tid = threadIdx.x;
  const int lane = tid & 63;
  const int wv = tid >> 6;
  const int quad = lane >> 4;
  const int col = lane & 15;
  const int swz = col & 7;
  const int bid = blockIdx.x;
  const int j0 = bid * UNITS;
  const int m0 = wv * 16;            // batch-row base for this wave (wave-owned)

  unsigned int* leaf = bar + wv * 512;   // this chain's 16 leaves (128B stride)

  // ---- stage W_ih slice (fp32 -> bf16, swizzled) into LDS ----
  for (int idx = tid; idx < 32 * INx; idx += 256) {
    int n = idx >> 9;
    int k = idx & (INx - 1);
    int row = ((n >> 3) * Hx) + j0 + (n & 7);
    int c = k >> 3;
    wsh[n * INx + (((c ^ (n & 7)) << 3) | (k & 7))] = f2bf(W_ih[row * INx + k]);
  }

  // ---- preload W_hh B-fragments into registers ----
  short8 wf[32][2];
#pragma unroll
  for (int kt = 0; kt < 32; ++kt) {
#pragma unroll
    for (int nt = 0; nt < 2; ++nt) {
      int n = nt * 16 + col;
      int row = ((n >> 3) * Hx) + j0 + (n & 7);
      const float* p = W_hh + row * Hx + kt * 32 + quad * 8;
      short8 w;
#pragma unroll
      for (int j = 0; j < 8; ++j) w[j] = (short)f2bf(p[j]);
      wf[kt][nt] = w;
    }
  }

  // ---- bias registers: thread owns (m=m0+col, units j0+2*quad+{0,1}) ----
  float bias[2][4];
#pragma unroll
  for (int p = 0; p < 2; ++p) {
    int jl = 2 * quad + p;
#pragma unroll
    for (int gt = 0; gt < 4; ++gt) {
      int row = gt * Hx + j0 + jl;
      bias[p][gt] = b_ih[row] + b_hh[row];
    }
  }

  float cst[2] = {0.0f, 0.0f};
  float hst[2] = {0.0f, 0.0f};

  // ---- prefetch x A-frags for t=0 ----
  short8 xa[16];
  {
    const unsigned short* xrow = xT + (m0 + col) * INx + quad * 8;
#pragma unroll
    for (int kt = 0; kt < 16; ++kt) xa[kt] = *(const short8*)(xrow + kt * 32);
  }

  __syncthreads();   // wsh staging complete (only pre-loop barrier)

  // ---- A(0): input part for t=0 (wsh ready, xa(0) loaded) ----
  floatx4 a0a = {0.f, 0.f, 0.f, 0.f}, a0b = {0.f, 0.f, 0.f, 0.f};
  floatx4 a1a = {0.f, 0.f, 0.f, 0.f}, a1b = {0.f, 0.f, 0.f, 0.f};
  {
    const short* b0base = wsh + col * INx;
    const short* b1base = wsh + (col + 16) * INx;
#pragma unroll
    for (int kt = 0; kt < 16; ++kt) {
      int off = (((kt << 2) | quad) ^ swz) << 3;
      short8 b0 = *(const short8*)(b0base + off);
      short8 b1 = *(const short8*)(b1base + off);
      if (kt & 1) {
        a0b = __builtin_amdgcn_mfma_f32_16x16x32_bf16(xa[kt], b0, a0b, 0, 0, 0);
        a1b = __builtin_amdgcn_mfma_f32_16x16x32_bf16(xa[kt], b1, a1b, 0, 0, 0);
      } else {
        a0a = __builtin_amdgcn_mfma_f32_16x16x32_bf16(xa[kt], b0, a0a, 0, 0, 0);
        a1a = __builtin_amdgcn_mfma_f32_16x16x32_bf16(xa[kt], b1, a1a, 0, 0, 0);
      }
    }
  }

  int ridx = 0;                      // buffer holding h(t)
  for (int t = 0; t < Tx; ++t) {
    // ---- B: wait for this chain's h(t): all 128 blocks' wave wv ----
    {
      unsigned target = (unsigned)t * 8u;   // 8 writers per leaf
      for (;;) {
        unsigned v = target;
        if (lane < 16)
          v = __hip_atomic_load(&leaf[lane * 32], __ATOMIC_RELAXED,
                                __HIP_MEMORY_SCOPE_AGENT);
        if (__all(v >= target)) break;
        __builtin_amdgcn_s_sleep(1);
      }
    }
    asm volatile("" ::: "memory");   // no DMA hoisting above the spin

    // every 64 steps: L2 invalidate so no stale line survives to an
    // h-buffer address reuse (reuse distance NBUF=65 > fence period 64,
    // so any reuse window contains >=1 acquire)
    if ((t & 63) == 0 && t) {
      __builtin_amdgcn_fence(__ATOMIC_ACQUIRE, "agent");
    }

    // ---- D: stage this wave's 16 h rows into LDS (cached, L2-shared) ----
    int widx = ridx + 1; if (widx == NBUF) widx = 0;
    const unsigned short* hin = hbuf + (size_t)ridx * (Bx * Hx);
    unsigned short* hout = hbuf + (size_t)widx * (Bx * Hx);
    ridx = widx;
#pragma unroll
    for (int r = 0; r < 16; ++r) {
      const unsigned short* g = hin + (m0 + r) * Hx + ((lane ^ (r & 7)) << 3);
      short* l = hsh + (m0 + r) * Hx;
      ASYNC_CP(g, l);
      ASYNC_CP(g + 512, l + 512);
    }

    // ---- E: x-prefetch for t+1 (overlaps DMA fill; consumed by A(t+1)
    //      at the end of this iteration) ----
    {
      int tn = (t + 1) & (Tx - 1);
      const unsigned short* xrow =
          xT + (size_t)tn * (Bx * INx) + (m0 + col) * INx + quad * 8;
#pragma unroll
      for (int kt = 0; kt < 16; ++kt) xa[kt] = *(const short8*)(xrow + kt * 32);
    }

    // DMA landed before reading hsh (also drains x-prefetch; both ~1 RT)
    asm volatile("s_waitcnt vmcnt(0)" ::: "memory");

    // ---- F: recurrent part: gates += h(t) . W_hh^T ----
    const short* ab = hsh + (m0 + col) * Hx;
#pragma unroll
    for (int kt = 0; kt < 32; ++kt) {
      short8 af = *(const short8*)(ab + ((((kt << 2) | quad) ^ swz) << 3));
      if (kt & 1) {
        a0b = __builtin_amdgcn_mfma_f32_16x16x32_bf16(af, wf[kt][0], a0b, 0, 0, 0);
        a1b = __builtin_amdgcn_mfma_f32_16x16x32_bf16(af, wf[kt][1], a1b, 0, 0, 0);
      } else {
        a0a = __builtin_amdgcn_mfma_f32_16x16x32_bf16(af, wf[kt][0], a0a, 0, 0, 0);
        a1a = __builtin_amdgcn_mfma_f32_16x16x32_bf16(af, wf[kt][1], a1a, 0, 0, 0);
      }
    }
    floatx4 acc0 = a0a + a0b;
    floatx4 acc1 = a1a + a1b;

    // ---- G: transpose gates via per-wave scratch on own h region ----
    float* gp = (float*)(hsh + wv * 16 * Hx);
#pragma unroll
    for (int i = 0; i < 4; ++i) {
      gp[(quad * 4 + i) * 33 + col] = acc0[i];
      gp[(quad * 4 + i) * 33 + 16 + col] = acc1[i];
    }

    // ---- H: activations; thread owns (m=m0+col, units jl=2*quad+{0,1}) ----
    unsigned int hpack = 0;
#pragma unroll
    for (int p = 0; p < 2; ++p) {
      int jl = 2 * quad + p;
      float gi = gp[col * 33 + jl] + bias[p][0];
      float gf = gp[col * 33 + 8 + jl] + bias[p][1];
      float gg = gp[col * 33 + 16 + jl] + bias[p][2];
      float go = gp[col * 33 + 24 + jl] + bias[p][3];
      float iv = sigm(gi);
      float fv = sigm(gf);
      float gv = tanh_(gg);
      float ov = sigm(go);
      float c = fv * cst[p] + iv * gv;
      cst[p] = c;
      float h = ov * tanh_(c);
      hst[p] = h;
      hpack |= ((unsigned int)f2bf(h)) << (16 * p);
    }
    // device-scope (sc1) packed store: write-through to LLC
    __hip_atomic_store(
        (unsigned int*)(hout + (m0 + col) * Hx + j0 + 2 * quad), hpack,
        __ATOMIC_RELAXED, __HIP_MEMORY_SCOPE_AGENT);

    // ---- A(t+1): input GEMM for the next step (LDS wsh + regs only, no
    //      vmem): hides the h-store drain below; off the post-poll path ----
    a0a = (floatx4){0.f, 0.f, 0.f, 0.f}; a0b = (floatx4){0.f, 0.f, 0.f, 0.f};
    a1a = (floatx4){0.f, 0.f, 0.f, 0.f}; a1b = (floatx4){0.f, 0.f, 0.f, 0.f};
    {
      const short* b0base = wsh + col * INx;
      const short* b1base = wsh + (col + 16) * INx;
#pragma unroll
      for (int kt = 0; kt < 16; ++kt) {
        int off = (((kt << 2) | quad) ^ swz) << 3;
        short8 b0 = *(const short8*)(b0base + off);
        short8 b1 = *(const short8*)(b1base + off);
        if (kt & 1) {
          a0b = __builtin_amdgcn_mfma_f32_16x16x32_bf16(xa[kt], b0, a0b, 0, 0, 0);
          a1b = __builtin_amdgcn_mfma_f32_16x16x32_bf16(xa[kt], b1, a1b, 0, 0, 0);
        } else {
          a0a = __builtin_amdgcn_mfma_f32_16x16x32_bf16(xa[kt], b0, a0a, 0, 0, 0);
          a1a = __builtin_amdgcn_mfma_f32_16x16x32_bf16(xa[kt], b1, a1a, 0, 0, 0);
        }
      }
    }

    // ---- I: per-wave drain + leaf signal (no block rendezvous) ----
    // vmcnt(0): h store at LLC (x-prefetch already drained at mid-drain);
    // lgkmcnt(0): gp scratch + A-loop wsh reads done (closes WAR against
    // next iteration's DMA into the same LDS region).
    asm volatile("s_waitcnt vmcnt(0) lgkmcnt(0)" ::: "memory");
    if (lane == 0) {
      __hip_atomic_fetch_add(&leaf[(bid & 15) * 32], 1u, __ATOMIC_RELAXED,
                             __HIP_MEMORY_SCOPE_AGENT);
    }
  }

  // ---- final h -> out [B][1][H] ----
#pragma unroll
  for (int p = 0; p < 2; ++p) {
    int jl = 2 * quad + p;
    out[(m0 + col) * Hx + j0 + jl] = hst[p];
  }
}

extern "C" void kernel_launch(void* const* d_in, const int* in_sizes, int n_in,
                              void* d_out, int out_size, void* d_ws, size_t ws_size,
                              hipStream_t stream) {
  const float* input = (const float*)d_in[0];   // [B][T][IN]
  const float* W_ih  = (const float*)d_in[1];   // [4H][IN]
  const float* W_hh  = (const float*)d_in[2];   // [4H][H]
  const float* b_ih  = (const float*)d_in[3];   // [4H]
  const float* b_hh  = (const float*)d_in[4];   // [4H]
  float* out = (float*)d_out;

  char* ws = (char*)d_ws;
  unsigned int* bar = (unsigned int*)ws;                          // 8 KB
  unsigned short* hbuf = (unsigned short*)(ws + 8192);            // 65 x 128 KB
  unsigned short* xT = (unsigned short*)(ws + (9u << 20));        // 32 MB @ +9 MB

  // zero 4 chains' leaves + h buffer 0 (initial state)
  hipMemsetAsync(ws, 0, 8192 + Bx * Hx * sizeof(unsigned short), stream);

  convert_x_kernel<<<(Bx * Tx * INx) / (256 * 8), 256, 0, stream>>>(input, xT);

  lstm_persistent<<<NBLK, 256, 0, stream>>>(W_ih, W_hh, b_ih, b_hh, xT, hbuf, bar, out);
}

// Round 3
// 3054.388 us; speedup vs baseline: 1.3915x; 1.3375x over previous
//
#include <hip/hip_runtime.h>
#include <hip/hip_bf16.h>

// LSTM: B=64, T=512, IN=512, H=1024, gates i,f,g,o.
// Persistent kernel, 128 blocks x 256 threads.
// R11: exact R8 skeleton (R9/R10 post-mortem: both restructures extended
// register live ranges in an allocation already pinned at the 256-VGPR cap
// -> spills -> scratch reloads on the serial F-path; visible as +54MB
// FETCH / +18MB WRITE, not in VGPR_Count. A-loop stays at the TOP of the
// loop; accumulators live only top->G; fence stays at 32 steps since
// fence-64 measurably did NOT reduce FETCH).
// ONE change vs R8, regalloc-neutral, targeting the sync chain:
//   SIGNAL: atomic-add leaf tree (16 same-word fetch_adds per leaf,
//   serialized RMWs at the LLC ~100-200cy each => last-signer tail
//   ~1600-3200cy on the critical chain) -> per-block monotone FLAG array.
//   Block bid / chain wv plain-stores flag[wv*128+bid]=t+1 after the
//   existing vmcnt drain (plain stores to distinct dwords in a line
//   coalesce at the LLC, no RMW serialization; monotone => no reset).
//   Poll: 64 lanes read 2 flags each (128 flags, 8 lines, LLC-resident
//   read-only traffic) and __all(>= t).
// R8 retained verbatim: wave-specialized chains (4 independent
// per-wave-index sync domains, no __syncthreads in the loop), 65 rotating
// h buffers, sc1 h stores, cached global_load_lds DMA, acquire fence every
// 32 steps, W_hh in regs, W_ih bf16 in LDS, XOR swizzle everywhere.

#define Bx 64
#define Tx 512
#define INx 512
#define Hx 1024
#define NBLK 128
#define UNITS 8
#define NBUF 65            // rotating h buffers

typedef __attribute__((ext_vector_type(8))) short short8;
typedef __attribute__((ext_vector_type(4))) float floatx4;

// normal cached direct-to-LDS copy (L2-allocating)
#define ASYNC_CP(gp, lp)                                                      \
  __builtin_amdgcn_global_load_lds(                                           \
      (const __attribute__((address_space(1))) void*)(gp),                    \
      (__attribute__((address_space(3))) void*)(lp), 16, 0, 0)

__device__ __forceinline__ unsigned short f2bf(float f) {
  unsigned u = __float_as_uint(f);
  u += 0x7FFFu + ((u >> 16) & 1u);   // round-to-nearest-even
  return (unsigned short)(u >> 16);
}
__device__ __forceinline__ float sigm(float x) { return 1.0f / (1.0f + __expf(-x)); }
__device__ __forceinline__ float tanh_(float x) { return 1.0f - 2.0f / (1.0f + __expf(2.0f * x)); }

// Convert input [B][T][IN] fp32 -> xT [T][B][IN] bf16
__global__ void convert_x_kernel(const float* __restrict__ in, unsigned short* __restrict__ xT) {
  int idx = blockIdx.x * 256 + threadIdx.x;
  int lin = idx * 8;
  int t = lin >> 15;
  int rem = lin & 32767;
  int b = rem >> 9;
  int k = rem & 511;
  const float* src = in + ((((b << 9) + t) << 9) + k);
  float4 lo = *(const float4*)src;
  float4 hi = *(const float4*)(src + 4);
  short8 o;
  o[0] = (short)f2bf(lo.x); o[1] = (short)f2bf(lo.y);
  o[2] = (short)f2bf(lo.z); o[3] = (short)f2bf(lo.w);
  o[4] = (short)f2bf(hi.x); o[5] = (short)f2bf(hi.y);
  o[6] = (short)f2bf(hi.z); o[7] = (short)f2bf(hi.w);
  *(short8*)(xT + lin) = o;
}

__global__ __launch_bounds__(256, 1) void lstm_persistent(
    const float* __restrict__ W_ih, const float* __restrict__ W_hh,
    const float* __restrict__ b_ih, const float* __restrict__ b_hh,
    const unsigned short* __restrict__ xT,   // [T][B][IN] bf16
    unsigned short* __restrict__ hbuf,       // [NBUF][B][H] bf16 (buf 0 zeroed)
    unsigned int* __restrict__ bar,          // 4 chains x 128 flags (2 KB)
    float* __restrict__ out)                 // [B][H] fp32
{
  // h: 64 rows x 1024 shorts, 16B-chunk c of row m at c^(m&7)   (128 KiB)
  // wih: 32 rows x 512 shorts, chunk c of row n at c^(n&7)      (32 KiB)
  __shared__ short hsh[Bx * Hx];
  __shared__ short wsh[32 * INx];

  const int tid = threadIdx.x;
  const int lane = tid & 63;
  const int wv = tid >> 6;
  const int quad = lane >> 4;
  const int col = lane & 15;
  const int swz = col & 7;
  const int bid = blockIdx.x;
  const int j0 = bid * UNITS;
  const int m0 = wv * 16;            // batch-row base for this wave (wave-owned)

  unsigned int* flg = bar + wv * 128;    // this chain's 128 per-block flags

  // ---- stage W_ih slice (fp32 -> bf16, swizzled) into LDS ----
  for (int idx = tid; idx < 32 * INx; idx += 256) {
    int n = idx >> 9;
    int k = idx & (INx - 1);
    int row = ((n >> 3) * Hx) + j0 + (n & 7);
    int c = k >> 3;
    wsh[n * INx + (((c ^ (n & 7)) << 3) | (k & 7))] = f2bf(W_ih[row * INx + k]);
  }

  // ---- preload W_hh B-fragments into registers ----
  short8 wf[32][2];
#pragma unroll
  for (int kt = 0; kt < 32; ++kt) {
#pragma unroll
    for (int nt = 0; nt < 2; ++nt) {
      int n = nt * 16 + col;
      int row = ((n >> 3) * Hx) + j0 + (n & 7);
      const float* p = W_hh + row * Hx + kt * 32 + quad * 8;
      short8 w;
#pragma unroll
      for (int j = 0; j < 8; ++j) w[j] = (short)f2bf(p[j]);
      wf[kt][nt] = w;
    }
  }

  // ---- bias registers: thread owns (m=m0+col, units j0+2*quad+{0,1}) ----
  float bias[2][4];
#pragma unroll
  for (int p = 0; p < 2; ++p) {
    int jl = 2 * quad + p;
#pragma unroll
    for (int gt = 0; gt < 4; ++gt) {
      int row = gt * Hx + j0 + jl;
      bias[p][gt] = b_ih[row] + b_hh[row];
    }
  }

  float cst[2] = {0.0f, 0.0f};
  float hst[2] = {0.0f, 0.0f};

  // ---- prefetch x A-frags for t=0 ----
  short8 xa[16];
  {
    const unsigned short* xrow = xT + (m0 + col) * INx + quad * 8;
#pragma unroll
    for (int kt = 0; kt < 16; ++kt) xa[kt] = *(const short8*)(xrow + kt * 32);
  }

  __syncthreads();   // wsh staging complete (only pre-loop barrier)

  int ridx = 0;                      // buffer holding h(t)
  for (int t = 0; t < Tx; ++t) {
    // ---- A: input part (no h dependency): gates = x_t . W_ih^T ----
    floatx4 a0a = {0.f, 0.f, 0.f, 0.f}, a0b = {0.f, 0.f, 0.f, 0.f};
    floatx4 a1a = {0.f, 0.f, 0.f, 0.f}, a1b = {0.f, 0.f, 0.f, 0.f};
    {
      const short* b0base = wsh + col * INx;
      const short* b1base = wsh + (col + 16) * INx;
#pragma unroll
      for (int kt = 0; kt < 16; ++kt) {
        int off = (((kt << 2) | quad) ^ swz) << 3;
        short8 b0 = *(const short8*)(b0base + off);
        short8 b1 = *(const short8*)(b1base + off);
        if (kt & 1) {
          a0b = __builtin_amdgcn_mfma_f32_16x16x32_bf16(xa[kt], b0, a0b, 0, 0, 0);
          a1b = __builtin_amdgcn_mfma_f32_16x16x32_bf16(xa[kt], b1, a1b, 0, 0, 0);
        } else {
          a0a = __builtin_amdgcn_mfma_f32_16x16x32_bf16(xa[kt], b0, a0a, 0, 0, 0);
          a1a = __builtin_amdgcn_mfma_f32_16x16x32_bf16(xa[kt], b1, a1a, 0, 0, 0);
        }
      }
    }

    // ---- B: wait for this chain's h(t): all 128 blocks' flags >= t ----
    // (contention-free: monotone per-block flags, plain agent stores;
    //  64 lanes x 2 loads cover all 128 flags)
    {
      unsigned target = (unsigned)t;
      for (;;) {
        unsigned v0 = __hip_atomic_load(&flg[2 * lane], __ATOMIC_RELAXED,
                                        __HIP_MEMORY_SCOPE_AGENT);
        unsigned v1 = __hip_atomic_load(&flg[2 * lane + 1], __ATOMIC_RELAXED,
                                        __HIP_MEMORY_SCOPE_AGENT);
        if (__all(v0 >= target && v1 >= target)) break;
        __builtin_amdgcn_s_sleep(1);
      }
    }
    asm volatile("" ::: "memory");   // no DMA hoisting above the spin

    // every 32 steps: L2 invalidate so no stale line survives to an
    // h-buffer address reuse (reuse distance NBUF=65 > 2 fence periods)
    if ((t & 31) == 0 && t) {
      __builtin_amdgcn_fence(__ATOMIC_ACQUIRE, "agent");
    }

    // ---- D: stage this wave's 16 h rows into LDS (cached, L2-shared) ----
    int widx = ridx + 1; if (widx == NBUF) widx = 0;
    const unsigned short* hin = hbuf + (size_t)ridx * (Bx * Hx);
    unsigned short* hout = hbuf + (size_t)widx * (Bx * Hx);
    ridx = widx;
#pragma unroll
    for (int r = 0; r < 16; ++r) {
      const unsigned short* g = hin + (m0 + r) * Hx + ((lane ^ (r & 7)) << 3);
      short* l = hsh + (m0 + r) * Hx;
      ASYNC_CP(g, l);
      ASYNC_CP(g + 512, l + 512);
    }

    // ---- E: x-prefetch for t+1 (overlaps DMA fill) ----
    {
      int tn = (t + 1) & (Tx - 1);
      const unsigned short* xrow =
          xT + (size_t)tn * (Bx * INx) + (m0 + col) * INx + quad * 8;
#pragma unroll
      for (int kt = 0; kt < 16; ++kt) xa[kt] = *(const short8*)(xrow + kt * 32);
    }

    // DMA landed before reading hsh (also drains x-prefetch; both ~1 RT)
    asm volatile("s_waitcnt vmcnt(0)" ::: "memory");

    // ---- F: recurrent part: gates += h(t) . W_hh^T ----
    const short* ab = hsh + (m0 + col) * Hx;
#pragma unroll
    for (int kt = 0; kt < 32; ++kt) {
      short8 af = *(const short8*)(ab + ((((kt << 2) | quad) ^ swz) << 3));
      if (kt & 1) {
        a0b = __builtin_amdgcn_mfma_f32_16x16x32_bf16(af, wf[kt][0], a0b, 0, 0, 0);
        a1b = __builtin_amdgcn_mfma_f32_16x16x32_bf16(af, wf[kt][1], a1b, 0, 0, 0);
      } else {
        a0a = __builtin_amdgcn_mfma_f32_16x16x32_bf16(af, wf[kt][0], a0a, 0, 0, 0);
        a1a = __builtin_amdgcn_mfma_f32_16x16x32_bf16(af, wf[kt][1], a1a, 0, 0, 0);
      }
    }
    floatx4 acc0 = a0a + a0b;
    floatx4 acc1 = a1a + a1b;

    // ---- G: transpose gates via per-wave scratch on own h region ----
    float* gp = (float*)(hsh + wv * 16 * Hx);
#pragma unroll
    for (int i = 0; i < 4; ++i) {
      gp[(quad * 4 + i) * 33 + col] = acc0[i];
      gp[(quad * 4 + i) * 33 + 16 + col] = acc1[i];
    }

    // ---- H: activations; thread owns (m=m0+col, units jl=2*quad+{0,1}) ----
    unsigned int hpack = 0;
#pragma unroll
    for (int p = 0; p < 2; ++p) {
      int jl = 2 * quad + p;
      float gi = gp[col * 33 + jl] + bias[p][0];
      float gf = gp[col * 33 + 8 + jl] + bias[p][1];
      float gg = gp[col * 33 + 16 + jl] + bias[p][2];
      float go = gp[col * 33 + 24 + jl] + bias[p][3];
      float iv = sigm(gi);
      float fv = sigm(gf);
      float gv = tanh_(gg);
      float ov = sigm(go);
      float c = fv * cst[p] + iv * gv;
      cst[p] = c;
      float h = ov * tanh_(c);
      hst[p] = h;
      hpack |= ((unsigned int)f2bf(h)) << (16 * p);
    }
    // device-scope (sc1) packed store: write-through to LLC
    __hip_atomic_store(
        (unsigned int*)(hout + (m0 + col) * Hx + j0 + 2 * quad), hpack,
        __ATOMIC_RELAXED, __HIP_MEMORY_SCOPE_AGENT);

    // ---- I: per-wave drain + flag signal (no block rendezvous) ----
    // vmcnt(0): h stores at LLC; lgkmcnt(0): gp scratch reads done (closes
    // WAR against next iteration's DMA into the same LDS region).
    asm volatile("s_waitcnt vmcnt(0) lgkmcnt(0)" ::: "memory");
    if (lane == 0) {
      __hip_atomic_store(&flg[bid], (unsigned)(t + 1), __ATOMIC_RELAXED,
                         __HIP_MEMORY_SCOPE_AGENT);
    }
  }

  // ---- final h -> out [B][1][H] ----
#pragma unroll
  for (int p = 0; p < 2; ++p) {
    int jl = 2 * quad + p;
    out[(m0 + col) * Hx + j0 + jl] = hst[p];
  }
}

extern "C" void kernel_launch(void* const* d_in, const int* in_sizes, int n_in,
                              void* d_out, int out_size, void* d_ws, size_t ws_size,
                              hipStream_t stream) {
  const float* input = (const float*)d_in[0];   // [B][T][IN]
  const float* W_ih  = (const float*)d_in[1];   // [4H][IN]
  const float* W_hh  = (const float*)d_in[2];   // [4H][H]
  const float* b_ih  = (const float*)d_in[3];   // [4H]
  const float* b_hh  = (const float*)d_in[4];   // [4H]
  float* out = (float*)d_out;

  char* ws = (char*)d_ws;
  unsigned int* bar = (unsigned int*)ws;                          // 2 KB flags
  unsigned short* hbuf = (unsigned short*)(ws + 8192);            // 65 x 128 KB
  unsigned short* xT = (unsigned short*)(ws + (9u << 20));        // 32 MB @ +9 MB

  // zero 4 chains' flags + h buffer 0 (initial state)
  hipMemsetAsync(ws, 0, 8192 + Bx * Hx * sizeof(unsigned short), stream);

  convert_x_kernel<<<(Bx * Tx * INx) / (256 * 8), 256, 0, stream>>>(input, xT);

  lstm_persistent<<<NBLK, 256, 0, stream>>>(W_ih, W_hh, b_ih, b_hh, xT, hbuf, bar, out);
}